// Round 4
// baseline (718.992 us; speedup 1.0000x reference)
//
#include <hip/hip_runtime.h>
#include <math.h>

#define VOCAB 2048
#define EMB 256
#define MAXLEN 8
#define NBATCH 16
#define LAT 16
#define NG4 8192      // 4*VOCAB
#define JC 16         // Wr row-chunks of 128
#define UBL 32        // u-slices of 64 (per gate)
#define KC 2          // Wk row-chunks of 128

// token = argmax_j ( j/2048 <= v && v <= (j+1)/2048 ), 0 if none.
// cumsum of uniform softmax is exactly k/2048 in fp32; v*2048 is exact.
__device__ __forceinline__ int token_of(float v) {
    float u = v * 2048.0f;
    if (!(u >= 0.0f) || u > 2048.0f) return 0;   // v<0, v>1, or NaN
    int k = (int)ceilf(u) - 1;
    return k < 0 ? 0 : k;
}

__device__ __forceinline__ float sigmoidf_(float x) { return 1.0f / (1.0f + expf(-x)); }

// ---- Kernel A: XT[t][k][b] = E[token(b,t)][k]; zero h, c; zero tickets ----
__global__ void k_init(const float* __restrict__ ip, const float* __restrict__ E,
                       float* __restrict__ XT, float* __restrict__ h,
                       float* __restrict__ c, int* __restrict__ ctr) {
    int idx = blockIdx.x * 256 + threadIdx.x;   // 0..32767
    int t = idx >> 12;
    int b = (idx >> 8) & 15;
    int k = idx & 255;
    int tok = token_of(ip[b * LAT + t]);
    XT[t * (EMB * NBATCH) + k * NBATCH + b] = E[tok * EMB + k];
    h[idx] = 0.0f;
    c[idx] = 0.0f;
    if (blockIdx.x == 0) ctr[threadIdx.x] = 0;   // 8*32 = 256 tickets
}

// ---- Kernel B: xz partials for ALL timesteps (bias folded into kc==0).
// grid = KC*8*UBL blocks of 256. block (kc,t,ub); wave g = gate; lane -> u.
__global__ __launch_bounds__(256) void k_xz(
        const float* __restrict__ Wk, const float* __restrict__ XT,
        const float* __restrict__ bv, float* __restrict__ xzp) {
    int bx = blockIdx.x;
    int ub = bx & (UBL - 1);
    int t  = (bx >> 5) & 7;
    int kc = bx >> 8;
    int tid = threadIdx.x;
    int g = tid >> 6;
    int lane = tid & 63;

    __shared__ __align__(16) float sh[128 * NBATCH];
    const float4* src = (const float4*)(XT + (t * EMB + kc * 128) * NBATCH);
    ((float4*)sh)[tid]       = src[tid];
    ((float4*)sh)[tid + 256] = src[tid + 256];
    __syncthreads();

    int u = ub * 64 + lane;
    const float* wp = Wk + (size_t)(kc * 128) * NG4 + g * 2048 + u;

    float acc[NBATCH];
    float binit = (kc == 0) ? bv[g * 2048 + u] : 0.0f;
    #pragma unroll
    for (int b = 0; b < NBATCH; ++b) acc[b] = binit;

    #pragma unroll 4
    for (int jl = 0; jl < 128; ++jl) {
        float w = wp[(size_t)jl * NG4];
        const float4* hp = (const float4*)(sh + jl * NBATCH);
        float4 h0 = hp[0], h1 = hp[1], h2 = hp[2], h3 = hp[3];
        float hb[NBATCH] = {h0.x,h0.y,h0.z,h0.w, h1.x,h1.y,h1.z,h1.w,
                            h2.x,h2.y,h2.z,h2.w, h3.x,h3.y,h3.z,h3.w};
        #pragma unroll
        for (int b = 0; b < NBATCH; ++b) acc[b] = fmaf(w, hb[b], acc[b]);
    }
    #pragma unroll
    for (int b = 0; b < NBATCH; ++b)
        xzp[(size_t)((kc * 8 + t) * NBATCH + b) * NG4 + g * 2048 + u] = acc[b];
}

// ---- Kernel C: step 0 (h==0): z = sum of xz chunks; gates; update; write hT1 ----
__global__ __launch_bounds__(256) void k_step0(
        const float* __restrict__ xzp, const float* __restrict__ ip,
        float* __restrict__ h, float* __restrict__ c,
        float* __restrict__ hTout, float* __restrict__ H) {
    int idx = blockIdx.x * 256 + threadIdx.x;
    int b = idx >> 11;
    int u = idx & 2047;
    float z[4];
    #pragma unroll
    for (int g = 0; g < 4; ++g) {
        z[g] = xzp[(size_t)(b) * NG4 + g * 2048 + u]                    // kc0,t0
             + xzp[(size_t)(8 * NBATCH + b) * NG4 + g * 2048 + u];      // kc1,t0
    }
    float cn = sigmoidf_(z[1]) * 0.0f + sigmoidf_(z[0]) * tanhf(z[2]);
    float hn = sigmoidf_(z[3]) * tanhf(cn);
    int tok = token_of(ip[b * LAT + 0]);
    float hw = tok != 0 ? hn : 0.0f;
    float cw = tok != 0 ? cn : 0.0f;
    h[idx] = hw;
    c[idx] = cw;
    hTout[u * NBATCH + b] = hw;
    H[idx] = hw;
}

// ---- Kernel D: fused Wr-GEMM + last-block-ticket reduce/update for step t>=1.
// grid = JC*UBL blocks of 256. block (jc,ub); wave g = gate; lane -> u.
// hTin = hTbuf[t&1] (read-only this launch); hTout = hTbuf[(t+1)&1].
__global__ __launch_bounds__(256) void k_gemm_fused(
        const float* __restrict__ Wr, const float* __restrict__ hTin,
        float* __restrict__ hTout, float* __restrict__ zp,
        const float* __restrict__ xzp, const float* __restrict__ ip,
        float* __restrict__ h, float* __restrict__ c,
        float* __restrict__ H, int* __restrict__ ctr, int t) {
    int bx = blockIdx.x;
    int ub = bx & (UBL - 1);
    int jc = bx >> 5;
    int tid = threadIdx.x;
    int g = tid >> 6;
    int lane = tid & 63;

    __shared__ __align__(16) float sh[128 * NBATCH];
    const float4* src = (const float4*)(hTin + jc * 128 * NBATCH);
    ((float4*)sh)[tid]       = src[tid];
    ((float4*)sh)[tid + 256] = src[tid + 256];
    __syncthreads();

    int u = ub * 64 + lane;
    const float* wp = Wr + (size_t)(jc * 128) * NG4 + g * 2048 + u;

    float acc[NBATCH];
    #pragma unroll
    for (int b = 0; b < NBATCH; ++b) acc[b] = 0.0f;

    #pragma unroll 4
    for (int jl = 0; jl < 128; ++jl) {
        float w = wp[(size_t)jl * NG4];
        const float4* hp = (const float4*)(sh + jl * NBATCH);
        float4 h0 = hp[0], h1 = hp[1], h2 = hp[2], h3 = hp[3];
        float hb[NBATCH] = {h0.x,h0.y,h0.z,h0.w, h1.x,h1.y,h1.z,h1.w,
                            h2.x,h2.y,h2.z,h2.w, h3.x,h3.y,h3.z,h3.w};
        #pragma unroll
        for (int b = 0; b < NBATCH; ++b) acc[b] = fmaf(w, hb[b], acc[b]);
    }
    #pragma unroll
    for (int b = 0; b < NBATCH; ++b)
        zp[(size_t)(jc * NBATCH + b) * NG4 + g * 2048 + u] = acc[b];

    // ---- ticket: last of the JC blocks for this ub does the reduction ----
    __threadfence();                       // release zp stores device-wide
    __shared__ int isLast;
    if (tid == 0) {
        int old = atomicAdd(&ctr[(t - 1) * UBL + ub], 1);
        isLast = (old == JC - 1) ? 1 : 0;
    }
    __syncthreads();
    if (!isLast) return;
    __threadfence();                       // acquire: see other blocks' zp

    // 64 u x 16 b items; 4 per thread; lane -> ul (coalesced)
    #pragma unroll 1
    for (int r = 0; r < 4; ++r) {
        int item = tid + r * 256;
        int ul = item & 63;
        int bq = item >> 6;
        int uu = ub * 64 + ul;
        float z[4];
        #pragma unroll
        for (int g2 = 0; g2 < 4; ++g2) {
            z[g2] = xzp[(size_t)((0 * 8 + t) * NBATCH + bq) * NG4 + g2 * 2048 + uu]
                  + xzp[(size_t)((1 * 8 + t) * NBATCH + bq) * NG4 + g2 * 2048 + uu];
        }
        #pragma unroll
        for (int jc2 = 0; jc2 < JC; ++jc2) {
            const float* p = zp + (size_t)(jc2 * NBATCH + bq) * NG4 + uu;
            z[0] += p[0];
            z[1] += p[2048];
            z[2] += p[4096];
            z[3] += p[6144];
        }
        int idx = bq * VOCAB + uu;
        float co = c[idx], ho = h[idx];
        float cn = sigmoidf_(z[1]) * co + sigmoidf_(z[0]) * tanhf(z[2]);
        float hn = sigmoidf_(z[3]) * tanhf(cn);
        int tok = token_of(ip[bq * LAT + t]);
        float hw = tok != 0 ? hn : ho;
        float cw = tok != 0 ? cn : co;
        h[idx] = hw;
        c[idx] = cw;
        hTout[uu * NBATCH + bq] = hw;
        H[(size_t)t * (NBATCH * VOCAB) + idx] = hw;
    }
}

// ---- Kernel E: softmax of all 128 recorded h rows -> d_out[b][t][:] ----
__global__ __launch_bounds__(256) void k_softmax(const float* __restrict__ H,
                                                 float* __restrict__ out) {
    int r = blockIdx.x;          // r = t*16 + b
    int t = r >> 4, b = r & 15;
    int tid = threadIdx.x;
    const float* hr = H + (size_t)r * VOCAB;
    float v[8];
    float m = -1e30f;
    #pragma unroll
    for (int i = 0; i < 8; ++i) { v[i] = hr[tid + i * 256]; m = fmaxf(m, v[i]); }

    __shared__ float redm[4], reds[4];
    int wid = tid >> 6, lane = tid & 63;
    #pragma unroll
    for (int off = 32; off; off >>= 1) m = fmaxf(m, __shfl_down(m, off));
    if (lane == 0) redm[wid] = m;
    __syncthreads();
    m = fmaxf(fmaxf(redm[0], redm[1]), fmaxf(redm[2], redm[3]));

    float e[8];
    float s = 0.0f;
    #pragma unroll
    for (int i = 0; i < 8; ++i) { e[i] = expf(v[i] - m); s += e[i]; }
    #pragma unroll
    for (int off = 32; off; off >>= 1) s += __shfl_down(s, off);
    if (lane == 0) reds[wid] = s;
    __syncthreads();
    s = reds[0] + reds[1] + reds[2] + reds[3];

    float* o = out + ((size_t)b * MAXLEN + t) * VOCAB;
    #pragma unroll
    for (int i = 0; i < 8; ++i) o[tid + i * 256] = e[i] / s;
}

extern "C" void kernel_launch(void* const* d_in, const int* in_sizes, int n_in,
                              void* d_out, int out_size, void* d_ws, size_t ws_size,
                              hipStream_t stream) {
    const float* ip = (const float*)d_in[0];   // (16,16)
    const float* E  = (const float*)d_in[1];   // (2048,256)
    const float* Wk = (const float*)d_in[2];   // (256,8192)
    const float* Wr = (const float*)d_in[3];   // (2048,8192)
    const float* bv = (const float*)d_in[4];   // (8192,)

    float* ws  = (float*)d_ws;
    float* XT  = ws;               // 8*256*16    = 32768
    float* h   = XT  + 32768;      // 16*2048     = 32768
    float* hT0 = h   + 32768;      // 2048*16     = 32768
    float* hT1 = hT0 + 32768;      // 2048*16     = 32768
    float* c   = hT1 + 32768;      // 16*2048     = 32768
    float* H   = c   + 32768;      // 8*16*2048   = 262144
    float* xzp = H   + 262144;     // 2*8*16*8192 = 2097152 (8.4 MB)
    float* zp  = xzp + 2097152;    // 16*16*8192  = 2097152 (8.4 MB)
    int*   ctr = (int*)(zp + 2097152);   // 8*32 tickets

    float* hTbuf[2] = {hT0, hT1};

    k_init<<<128, 256, 0, stream>>>(ip, E, XT, h, c, ctr);
    k_xz<<<KC * 8 * UBL, 256, 0, stream>>>(Wk, XT, bv, xzp);
    k_step0<<<128, 256, 0, stream>>>(xzp, ip, h, c, hT1, H);
    for (int t = 1; t < MAXLEN; ++t) {
        k_gemm_fused<<<JC * UBL, 256, 0, stream>>>(
            Wr, hTbuf[t & 1], hTbuf[(t + 1) & 1], zp, xzp, ip, h, c, H, ctr, t);
    }
    k_softmax<<<128, 256, 0, stream>>>(H, (float*)d_out);
}

// Round 5
// 328.767 us; speedup vs baseline: 2.1869x; 2.1869x over previous
//
#include <hip/hip_runtime.h>
#include <math.h>

#define VOCAB 2048
#define EMB 256
#define MAXLEN 8
#define NBATCH 16
#define LAT 16
#define NG4 8192      // 4*VOCAB
#define JC 32         // Wr row-chunks of 64
#define KCX 4         // Wk row-chunks of 64

// token = argmax_j ( j/2048 <= v && v <= (j+1)/2048 ), 0 if none.
// cumsum of uniform softmax is exactly k/2048 in fp32; v*2048 is exact.
__device__ __forceinline__ int token_of(float v) {
    float u = v * 2048.0f;
    if (!(u >= 0.0f) || u > 2048.0f) return 0;   // v<0, v>1, or NaN
    int k = (int)ceilf(u) - 1;
    return k < 0 ? 0 : k;
}

__device__ __forceinline__ float sigmoidf_(float x) { return 1.0f / (1.0f + expf(-x)); }

// ---- Kernel A: XT[t][k][b] = E[token(b,t)][k] ----
__global__ void k_init(const float* __restrict__ ip, const float* __restrict__ E,
                       float* __restrict__ XT) {
    int idx = blockIdx.x * 256 + threadIdx.x;   // 0..32767
    int t = idx >> 12;
    int k = (idx >> 4) & 255;
    int b = idx & 15;
    int tok = token_of(ip[b * LAT + t]);
    XT[idx] = E[tok * EMB + k];
}

// ---- Kernel B: xz partials for ALL timesteps, 4 gates/thread, bias at kc==0.
// grid = 8t * KCX * 8ub = 256 blocks of 256. u = ub*256 + tid.
__global__ __launch_bounds__(256) void k_xz(
        const float* __restrict__ Wk, const float* __restrict__ XT,
        const float* __restrict__ bv, float* __restrict__ xzp) {
    int bx = blockIdx.x;
    int ub = bx & 7;
    int kc = (bx >> 3) & 3;
    int t  = bx >> 5;
    int tid = threadIdx.x;
    int u = ub * 256 + tid;

    __shared__ __align__(16) float sh[64 * NBATCH];
    ((float4*)sh)[tid] = ((const float4*)(XT + (t * EMB + kc * 64) * NBATCH))[tid];
    __syncthreads();

    const float* wbase = Wk + (size_t)(kc * 64) * NG4 + u;
    float acc[4][NBATCH];
    #pragma unroll
    for (int g = 0; g < 4; ++g) {
        float bi = (kc == 0) ? bv[g * 2048 + u] : 0.0f;
        #pragma unroll
        for (int b = 0; b < NBATCH; ++b) acc[g][b] = bi;
    }

    #pragma unroll 2
    for (int jl = 0; jl < 64; ++jl) {
        const float* wr = wbase + (size_t)jl * NG4;
        float wg[4] = {wr[0], wr[2048], wr[4096], wr[6144]};
        const float4* hp = (const float4*)(sh + jl * NBATCH);
        float4 h0 = hp[0], h1 = hp[1], h2 = hp[2], h3 = hp[3];
        float hb[NBATCH] = {h0.x,h0.y,h0.z,h0.w, h1.x,h1.y,h1.z,h1.w,
                            h2.x,h2.y,h2.z,h2.w, h3.x,h3.y,h3.z,h3.w};
        #pragma unroll
        for (int g = 0; g < 4; ++g)
            #pragma unroll
            for (int b = 0; b < NBATCH; ++b)
                acc[g][b] = fmaf(wg[g], hb[b], acc[g][b]);
    }
    #pragma unroll
    for (int g = 0; g < 4; ++g)
        #pragma unroll
        for (int b = 0; b < NBATCH; ++b)
            xzp[(size_t)((t * KCX + kc) * NBATCH + b) * NG4 + g * 2048 + u] = acc[g][b];
}

// ---- Kernel C: Wr partials, 4 gates/thread, LDS-staged hT broadcast.
// grid = JC * 8ub = 256 blocks of 256. u = ub*256 + tid.
__global__ __launch_bounds__(256) void k_gemm(
        const float* __restrict__ Wr, const float* __restrict__ hT,
        float* __restrict__ zp) {
    int bx = blockIdx.x;
    int ub = bx & 7;
    int jc = bx >> 3;
    int tid = threadIdx.x;
    int u = ub * 256 + tid;

    __shared__ __align__(16) float sh[64 * NBATCH];
    ((float4*)sh)[tid] = ((const float4*)(hT + jc * 64 * NBATCH))[tid];
    __syncthreads();

    const float* wbase = Wr + (size_t)(jc * 64) * NG4 + u;
    float acc[4][NBATCH];
    #pragma unroll
    for (int g = 0; g < 4; ++g)
        #pragma unroll
        for (int b = 0; b < NBATCH; ++b) acc[g][b] = 0.0f;

    #pragma unroll 2
    for (int jl = 0; jl < 64; ++jl) {
        const float* wr = wbase + (size_t)jl * NG4;
        float wg[4] = {wr[0], wr[2048], wr[4096], wr[6144]};
        const float4* hp = (const float4*)(sh + jl * NBATCH);
        float4 h0 = hp[0], h1 = hp[1], h2 = hp[2], h3 = hp[3];
        float hb[NBATCH] = {h0.x,h0.y,h0.z,h0.w, h1.x,h1.y,h1.z,h1.w,
                            h2.x,h2.y,h2.z,h2.w, h3.x,h3.y,h3.z,h3.w};
        #pragma unroll
        for (int g = 0; g < 4; ++g)
            #pragma unroll
            for (int b = 0; b < NBATCH; ++b)
                acc[g][b] = fmaf(wg[g], hb[b], acc[g][b]);
    }
    #pragma unroll
    for (int g = 0; g < 4; ++g)
        #pragma unroll
        for (int b = 0; b < NBATCH; ++b)
            zp[(size_t)(jc * NBATCH + b) * NG4 + g * 2048 + u] = acc[g][b];
}

// ---- Kernel D0: step 0 (h==c==0): z = xz(t=0); gates; write h,c,hT,H[0] ----
__global__ __launch_bounds__(256) void k_step0(
        const float* __restrict__ xzp, const float* __restrict__ ip,
        float* __restrict__ h, float* __restrict__ c,
        float* __restrict__ hT, float* __restrict__ H) {
    int idx = blockIdx.x * 256 + threadIdx.x;
    int b = idx >> 11;
    int u = idx & 2047;
    float z[4] = {0.f, 0.f, 0.f, 0.f};
    #pragma unroll
    for (int s = 0; s < KCX; ++s) {
        const float* p = xzp + (size_t)(s * NBATCH + b) * NG4 + u;
        #pragma unroll
        for (int g = 0; g < 4; ++g) z[g] += p[g * 2048];
    }
    float cn = sigmoidf_(z[0]) * tanhf(z[2]);
    float hn = sigmoidf_(z[3]) * tanhf(cn);
    int tok = token_of(ip[b * LAT + 0]);
    float hw = tok != 0 ? hn : 0.0f;
    float cw = tok != 0 ? cn : 0.0f;
    h[idx] = hw;
    c[idx] = cw;
    hT[u * NBATCH + b] = hw;
    H[idx] = hw;
}

// ---- Kernel D: reduce zp + xz(t); gates; masked update; write h,c,hT,H[t] ----
__global__ __launch_bounds__(256) void k_update(
        const float* __restrict__ zp, const float* __restrict__ xzp,
        const float* __restrict__ ip, float* __restrict__ h,
        float* __restrict__ c, float* __restrict__ hT,
        float* __restrict__ H, int t) {
    int idx = blockIdx.x * 256 + threadIdx.x;
    int b = idx >> 11;
    int u = idx & 2047;
    float z[4] = {0.f, 0.f, 0.f, 0.f};
    #pragma unroll
    for (int s = 0; s < KCX; ++s) {
        const float* p = xzp + (size_t)((t * KCX + s) * NBATCH + b) * NG4 + u;
        #pragma unroll
        for (int g = 0; g < 4; ++g) z[g] += p[g * 2048];
    }
    #pragma unroll 4
    for (int jc = 0; jc < JC; ++jc) {
        const float* p = zp + (size_t)(jc * NBATCH + b) * NG4 + u;
        z[0] += p[0];
        z[1] += p[2048];
        z[2] += p[4096];
        z[3] += p[6144];
    }
    float co = c[idx], ho = h[idx];
    float cn = sigmoidf_(z[1]) * co + sigmoidf_(z[0]) * tanhf(z[2]);
    float hn = sigmoidf_(z[3]) * tanhf(cn);
    int tok = token_of(ip[b * LAT + t]);
    float hw = tok != 0 ? hn : ho;
    float cw = tok != 0 ? cn : co;
    h[idx] = hw;
    c[idx] = cw;
    hT[u * NBATCH + b] = hw;
    H[(size_t)t * (NBATCH * VOCAB) + idx] = hw;
}

// ---- Kernel E: softmax of all 128 recorded h rows -> d_out[b][t][:] ----
__global__ __launch_bounds__(256) void k_softmax(const float* __restrict__ H,
                                                 float* __restrict__ out) {
    int r = blockIdx.x;          // r = t*16 + b
    int t = r >> 4, b = r & 15;
    int tid = threadIdx.x;
    const float* hr = H + (size_t)r * VOCAB;
    float v[8];
    float m = -1e30f;
    #pragma unroll
    for (int i = 0; i < 8; ++i) { v[i] = hr[tid + i * 256]; m = fmaxf(m, v[i]); }

    __shared__ float redm[4], reds[4];
    int wid = tid >> 6, lane = tid & 63;
    #pragma unroll
    for (int off = 32; off; off >>= 1) m = fmaxf(m, __shfl_down(m, off));
    if (lane == 0) redm[wid] = m;
    __syncthreads();
    m = fmaxf(fmaxf(redm[0], redm[1]), fmaxf(redm[2], redm[3]));

    float e[8];
    float s = 0.0f;
    #pragma unroll
    for (int i = 0; i < 8; ++i) { e[i] = expf(v[i] - m); s += e[i]; }
    #pragma unroll
    for (int off = 32; off; off >>= 1) s += __shfl_down(s, off);
    if (lane == 0) reds[wid] = s;
    __syncthreads();
    s = reds[0] + reds[1] + reds[2] + reds[3];

    float* o = out + ((size_t)b * MAXLEN + t) * VOCAB;
    #pragma unroll
    for (int i = 0; i < 8; ++i) o[tid + i * 256] = e[i] / s;
}

extern "C" void kernel_launch(void* const* d_in, const int* in_sizes, int n_in,
                              void* d_out, int out_size, void* d_ws, size_t ws_size,
                              hipStream_t stream) {
    const float* ip = (const float*)d_in[0];   // (16,16)
    const float* E  = (const float*)d_in[1];   // (2048,256)
    const float* Wk = (const float*)d_in[2];   // (256,8192)
    const float* Wr = (const float*)d_in[3];   // (2048,8192)
    const float* bv = (const float*)d_in[4];   // (8192,)

    float* ws  = (float*)d_ws;
    float* XT  = ws;               // 8*256*16        = 32768
    float* h   = XT  + 32768;      // 16*2048         = 32768
    float* hT  = h   + 32768;      // 2048*16         = 32768
    float* c   = hT  + 32768;      // 16*2048         = 32768
    float* H   = c   + 32768;      // 8*16*2048       = 262144
    float* xzp = H   + 262144;     // 8*4*16*8192     = 4194304 (16.8 MB)
    float* zp  = xzp + 4194304;    // 32*16*8192      = 4194304 (16.8 MB)

    k_init<<<128, 256, 0, stream>>>(ip, E, XT);
    k_xz<<<256, 256, 0, stream>>>(Wk, XT, bv, xzp);
    k_step0<<<128, 256, 0, stream>>>(xzp, ip, h, c, hT, H);
    for (int t = 1; t < MAXLEN; ++t) {
        k_gemm<<<256, 256, 0, stream>>>(Wr, hT, zp);
        k_update<<<128, 256, 0, stream>>>(zp, xzp, ip, h, c, hT, H, t);
    }
    k_softmax<<<128, 256, 0, stream>>>(H, (float*)d_out);
}

// Round 6
// 189.098 us; speedup vs baseline: 3.8022x; 1.7386x over previous
//
#include <hip/hip_runtime.h>
#include <math.h>

#define VOCAB 2048
#define EMB 256
#define MAXLEN 8
#define NBATCH 16
#define LAT 16
#define NG4 8192      // 4*VOCAB
#define JC 32         // Wr row-chunks of 64
#define KCX 4         // Wk row-chunks of 64
#define UBN 16        // u-blocks of 128 (64 lanes x float2) per gate

// token = argmax_j ( j/2048 <= v && v <= (j+1)/2048 ), 0 if none.
// cumsum of uniform softmax is exactly k/2048 in fp32; v*2048 is exact.
__device__ __forceinline__ int token_of(float v) {
    float u = v * 2048.0f;
    if (!(u >= 0.0f) || u > 2048.0f) return 0;   // v<0, v>1, or NaN
    int k = (int)ceilf(u) - 1;
    return k < 0 ? 0 : k;
}

__device__ __forceinline__ float sigmoidf_(float x) { return 1.0f / (1.0f + expf(-x)); }

// ---- Kernel A: XT[t][k][b] = E[token(b,t)][k] (staging-friendly layout) ----
__global__ void k_init(const float* __restrict__ ip, const float* __restrict__ E,
                       float* __restrict__ XT) {
    int idx = blockIdx.x * 256 + threadIdx.x;   // 0..32767
    int t = idx >> 12;
    int k = (idx >> 4) & 255;
    int b = idx & 15;
    int tok = token_of(ip[b * LAT + t]);
    XT[idx] = E[tok * EMB + k];
}

// ---- Kernel B: xz partials for ALL timesteps (bias folded into kc==0).
// grid = KCX*8t*UBN = 512 blocks of 256. wave g = gate; lane -> u pair.
__global__ __launch_bounds__(256) void k_xz(
        const float* __restrict__ Wk, const float* __restrict__ XT,
        const float* __restrict__ bv, float* __restrict__ xzp) {
    int bx = blockIdx.x;
    int ub = bx & (UBN - 1);
    int t  = (bx >> 4) & 7;
    int kc = bx >> 7;
    int tid = threadIdx.x;
    int g = tid >> 6;
    int lane = tid & 63;

    __shared__ __align__(16) float sh[64 * NBATCH];
    ((float4*)sh)[tid] = ((const float4*)(XT + (t * EMB + kc * 64) * NBATCH))[tid];
    __syncthreads();

    int u = ub * 128 + lane * 2;
    const float* wp = Wk + (size_t)(kc * 64) * NG4 + g * 2048 + u;

    float binit = (kc == 0) ? 0.0f : 0.0f;
    float2 bi = make_float2(0.f, 0.f);
    if (kc == 0) bi = *(const float2*)&bv[g * 2048 + u];
    (void)binit;

    float acc[NBATCH][2];
    #pragma unroll
    for (int b = 0; b < NBATCH; ++b) { acc[b][0] = bi.x; acc[b][1] = bi.y; }

    #pragma unroll 8
    for (int jl = 0; jl < 64; ++jl) {
        float2 w = *(const float2*)(wp + (size_t)jl * NG4);
        const float4* hp = (const float4*)(sh + jl * NBATCH);
        float4 h0 = hp[0], h1 = hp[1], h2 = hp[2], h3 = hp[3];
        float hb[NBATCH] = {h0.x,h0.y,h0.z,h0.w, h1.x,h1.y,h1.z,h1.w,
                            h2.x,h2.y,h2.z,h2.w, h3.x,h3.y,h3.z,h3.w};
        #pragma unroll
        for (int b = 0; b < NBATCH; ++b) {
            acc[b][0] = fmaf(w.x, hb[b], acc[b][0]);
            acc[b][1] = fmaf(w.y, hb[b], acc[b][1]);
        }
    }
    #pragma unroll
    for (int b = 0; b < NBATCH; ++b)
        *(float2*)&xzp[(size_t)((t * KCX + kc) * NBATCH + b) * NG4 + g * 2048 + u] =
            make_float2(acc[b][0], acc[b][1]);
}

// ---- Kernel C: Wr partials (round-2 structure + coalesced hT staging).
// grid = JC*UBN = 512 blocks of 256. wave g = gate; lane -> u pair.
__global__ __launch_bounds__(256) void k_gemm(
        const float* __restrict__ Wr, const float* __restrict__ hT,
        float* __restrict__ zp) {
    int bx = blockIdx.x;
    int ub = bx & (UBN - 1);
    int jc = bx >> 4;
    int tid = threadIdx.x;
    int g = tid >> 6;
    int lane = tid & 63;

    __shared__ __align__(16) float sh[64 * NBATCH];
    ((float4*)sh)[tid] = ((const float4*)(hT + jc * 64 * NBATCH))[tid];
    __syncthreads();

    int u = ub * 128 + lane * 2;
    const float* wp = Wr + (size_t)(jc * 64) * NG4 + g * 2048 + u;

    float acc[NBATCH][2];
    #pragma unroll
    for (int b = 0; b < NBATCH; ++b) { acc[b][0] = 0.0f; acc[b][1] = 0.0f; }

    #pragma unroll 8
    for (int jl = 0; jl < 64; ++jl) {
        float2 w = *(const float2*)(wp + (size_t)jl * NG4);
        const float4* hp = (const float4*)(sh + jl * NBATCH);
        float4 h0 = hp[0], h1 = hp[1], h2 = hp[2], h3 = hp[3];
        float hb[NBATCH] = {h0.x,h0.y,h0.z,h0.w, h1.x,h1.y,h1.z,h1.w,
                            h2.x,h2.y,h2.z,h2.w, h3.x,h3.y,h3.z,h3.w};
        #pragma unroll
        for (int b = 0; b < NBATCH; ++b) {
            acc[b][0] = fmaf(w.x, hb[b], acc[b][0]);
            acc[b][1] = fmaf(w.y, hb[b], acc[b][1]);
        }
    }
    #pragma unroll
    for (int b = 0; b < NBATCH; ++b)
        *(float2*)&zp[(size_t)(jc * NBATCH + b) * NG4 + g * 2048 + u] =
            make_float2(acc[b][0], acc[b][1]);
}

// ---- Kernel D0: step 0 (h==c==0): z = sum xz(t=0); gates; write h,c,hT,H[0] ----
__global__ __launch_bounds__(256) void k_step0(
        const float* __restrict__ xzp, const float* __restrict__ ip,
        float* __restrict__ h, float* __restrict__ c,
        float* __restrict__ hT, float* __restrict__ H) {
    int idx = blockIdx.x * 256 + threadIdx.x;
    int b = idx >> 11;
    int u = idx & 2047;
    float z[4] = {0.f, 0.f, 0.f, 0.f};
    #pragma unroll
    for (int kc = 0; kc < KCX; ++kc) {
        const float* p = xzp + (size_t)(kc * NBATCH + b) * NG4 + u;
        #pragma unroll
        for (int g = 0; g < 4; ++g) z[g] += p[g * 2048];
    }
    float cn = sigmoidf_(z[0]) * tanhf(z[2]);
    float hn = sigmoidf_(z[3]) * tanhf(cn);
    int tok = token_of(ip[b * LAT + 0]);
    float hw = tok != 0 ? hn : 0.0f;
    float cw = tok != 0 ? cn : 0.0f;
    h[idx] = hw;
    c[idx] = cw;
    hT[u * NBATCH + b] = hw;
    H[idx] = hw;
}

// ---- Kernel D: reduce zp + xz(t); gates; masked update; write h,c,hT,H[t].
// grid = 128 blocks x 1024 threads: block (b, ug); thread (g, ul).
__global__ __launch_bounds__(1024) void k_update(
        const float* __restrict__ zp, const float* __restrict__ xzp,
        const float* __restrict__ ip, float* __restrict__ h,
        float* __restrict__ c, float* __restrict__ hT,
        float* __restrict__ H, int t) {
    int b  = blockIdx.x >> 3;
    int ug = blockIdx.x & 7;
    int g  = threadIdx.x >> 8;
    int ul = threadIdx.x & 255;
    int u  = ug * 256 + ul;

    float z = 0.0f;
    #pragma unroll
    for (int kc = 0; kc < KCX; ++kc)
        z += xzp[(size_t)((t * KCX + kc) * NBATCH + b) * NG4 + g * 2048 + u];
    const float* p = zp + (size_t)g * 2048 + u + (size_t)b * NG4;
    #pragma unroll
    for (int jc = 0; jc < JC; ++jc) z += p[(size_t)jc * NBATCH * NG4];

    __shared__ float sz[4][256];
    sz[g][ul] = z;
    __syncthreads();

    if (g == 0) {
        float zi = sz[0][ul], zf = sz[1][ul], zg = sz[2][ul], zo = sz[3][ul];
        int idx = b * VOCAB + u;
        float co = c[idx], ho = h[idx];
        float cn = sigmoidf_(zf) * co + sigmoidf_(zi) * tanhf(zg);
        float hn = sigmoidf_(zo) * tanhf(cn);
        int tok = token_of(ip[b * LAT + t]);
        float hw = tok != 0 ? hn : ho;
        float cw = tok != 0 ? cn : co;
        h[idx] = hw;
        c[idx] = cw;
        hT[u * NBATCH + b] = hw;
        H[(size_t)t * (NBATCH * VOCAB) + idx] = hw;
    }
}

// ---- Kernel E: softmax of all 128 recorded h rows -> d_out[b][t][:] ----
__global__ __launch_bounds__(256) void k_softmax(const float* __restrict__ H,
                                                 float* __restrict__ out) {
    int r = blockIdx.x;          // r = t*16 + b
    int t = r >> 4, b = r & 15;
    int tid = threadIdx.x;
    const float* hr = H + (size_t)r * VOCAB;
    float v[8];
    float m = -1e30f;
    #pragma unroll
    for (int i = 0; i < 8; ++i) { v[i] = hr[tid + i * 256]; m = fmaxf(m, v[i]); }

    __shared__ float redm[4], reds[4];
    int wid = tid >> 6, lane = tid & 63;
    #pragma unroll
    for (int off = 32; off; off >>= 1) m = fmaxf(m, __shfl_down(m, off));
    if (lane == 0) redm[wid] = m;
    __syncthreads();
    m = fmaxf(fmaxf(redm[0], redm[1]), fmaxf(redm[2], redm[3]));

    float e[8];
    float s = 0.0f;
    #pragma unroll
    for (int i = 0; i < 8; ++i) { e[i] = expf(v[i] - m); s += e[i]; }
    #pragma unroll
    for (int off = 32; off; off >>= 1) s += __shfl_down(s, off);
    if (lane == 0) reds[wid] = s;
    __syncthreads();
    s = reds[0] + reds[1] + reds[2] + reds[3];

    float* o = out + ((size_t)b * MAXLEN + t) * VOCAB;
    #pragma unroll
    for (int i = 0; i < 8; ++i) o[tid + i * 256] = e[i] / s;
}

extern "C" void kernel_launch(void* const* d_in, const int* in_sizes, int n_in,
                              void* d_out, int out_size, void* d_ws, size_t ws_size,
                              hipStream_t stream) {
    const float* ip = (const float*)d_in[0];   // (16,16)
    const float* E  = (const float*)d_in[1];   // (2048,256)
    const float* Wk = (const float*)d_in[2];   // (256,8192)
    const float* Wr = (const float*)d_in[3];   // (2048,8192)
    const float* bv = (const float*)d_in[4];   // (8192,)

    float* ws  = (float*)d_ws;
    float* XT  = ws;               // 8*256*16        = 32768
    float* h   = XT  + 32768;      // 16*2048         = 32768
    float* hT  = h   + 32768;      // 2048*16         = 32768
    float* c   = hT  + 32768;      // 16*2048         = 32768
    float* H   = c   + 32768;      // 8*16*2048       = 262144
    float* xzp = H   + 262144;     // 8*4*16*8192     = 4194304 (16.8 MB)
    float* zp  = xzp + 4194304;    // 32*16*8192      = 4194304 (16.8 MB)

    k_init<<<128, 256, 0, stream>>>(ip, E, XT);
    k_xz<<<KCX * 8 * UBN, 256, 0, stream>>>(Wk, XT, bv, xzp);
    k_step0<<<128, 256, 0, stream>>>(xzp, ip, h, c, hT, H);
    for (int t = 1; t < MAXLEN; ++t) {
        k_gemm<<<JC * UBN, 256, 0, stream>>>(Wr, hT, zp);
        k_update<<<128, 1024, 0, stream>>>(zp, xzp, ip, h, c, hT, H, t);
    }
    k_softmax<<<128, 256, 0, stream>>>(H, (float*)d_out);
}

// Round 7
// 92.246 us; speedup vs baseline: 7.7943x; 2.0499x over previous
//
#include <hip/hip_runtime.h>
#include <hip/hip_bf16.h>
#include <math.h>

#define VOCAB 2048
#define EMB 256
#define MAXLEN 8
#define NBATCH 16
#define LAT 16

typedef unsigned short u16;
using bf16x8 = __attribute__((ext_vector_type(8))) short;
using f32x4  = __attribute__((ext_vector_type(4))) float;

// token = argmax_j ( j/2048 <= v && v <= (j+1)/2048 ), 0 if none.
// cumsum of uniform softmax is exactly k/2048 in fp32; v*2048 is exact.
__device__ __forceinline__ int token_of(float v) {
    float u = v * 2048.0f;
    if (!(u >= 0.0f) || u > 2048.0f) return 0;   // v<0, v>1, or NaN
    int k = (int)ceilf(u) - 1;
    return k < 0 ? 0 : k;
}

__device__ __forceinline__ float sigmoidf_(float x) { return 1.0f / (1.0f + expf(-x)); }

__device__ __forceinline__ u16 to_bf16(float x) {
    __hip_bfloat16 hb = __float2bfloat16(x);   // RTNE
    return *reinterpret_cast<u16*>(&hb);
}

// ---- Kernel CVT: pack W (K x 8192 fp32, K = 32<<sh) into MFMA-B fragment order.
// dst[((ntile*nk0 + k0)*64 + l)*8 + i] = bf16( W[(k0*32 + 8*(l>>4) + i)*8192 + ntile*16 + (l&15)] )
// (assumed per-lane k-map k = 8*(l>>4)+i; any k-permutation cancels since A uses the same map)
__global__ __launch_bounds__(256) void k_cvt(const float* __restrict__ W,
                                             u16* __restrict__ dst, int sh) {
    int gidx = blockIdx.x * 256 + threadIdx.x;
    int l = gidx & 63;
    int k0 = (gidx >> 6) & ((1 << sh) - 1);
    int ntile = gidx >> (6 + sh);
    int col = ntile * 16 + (l & 15);
    int row0 = k0 * 32 + 8 * (l >> 4);
    const float* s = W + (size_t)row0 * 8192 + col;
    u16 o[8];
    #pragma unroll
    for (int i = 0; i < 8; ++i) o[i] = to_bf16(s[(size_t)i * 8192]);
    *(uint4*)(dst + (size_t)gidx * 8) = *(uint4*)o;
}

// ---- Kernel A: pack X = E[token] into MFMA-A fragment order (bf16).
// XA[((t*8 + k0)*64 + l)*8 + i] = bf16( E[tok(b=l&15, t)][k0*32 + 8*(l>>4) + i] )
__global__ __launch_bounds__(256) void k_init(const float* __restrict__ ip,
                                              const float* __restrict__ E,
                                              u16* __restrict__ XA) {
    int gidx = blockIdx.x * 256 + threadIdx.x;   // 0..4095
    int l = gidx & 63;
    int k0 = (gidx >> 6) & 7;
    int t = gidx >> 9;
    int b = l & 15;
    int tok = token_of(ip[b * LAT + t]);
    const float* s = E + (size_t)tok * EMB + k0 * 32 + 8 * (l >> 4);
    u16 o[8];
    #pragma unroll
    for (int i = 0; i < 8; ++i) o[i] = to_bf16(s[i]);
    *(uint4*)(XA + (size_t)gidx * 8) = *(uint4*)o;
}

// ---- Kernel B: xz[t][g][b][u] = bias + X[t] @ Wk, all 8 timesteps via MFMA.
// grid = 512 ntiles x 512 thr (8 waves = 8 timesteps).
__global__ __launch_bounds__(512) void k_xzmm(const u16* __restrict__ BWk,
                                              const u16* __restrict__ XA,
                                              const float* __restrict__ bv,
                                              float* __restrict__ xz) {
    int ntile = blockIdx.x;          // 0..511 (n = ntile*16 + (l&15), n = g*2048+u)
    int t = threadIdx.x >> 6;        // 0..7
    int l = threadIdx.x & 63;
    float bias = bv[ntile * 16 + (l & 15)];
    f32x4 acc = {bias, bias, bias, bias};
    const bf16x8* ap = (const bf16x8*)(XA + ((size_t)(t * 8) * 64 + l) * 8);
    const bf16x8* bp = (const bf16x8*)(BWk + ((size_t)(ntile * 8) * 64 + l) * 8);
    #pragma unroll
    for (int s = 0; s < 8; ++s)
        acc = __builtin_amdgcn_mfma_f32_16x16x32_bf16(ap[s * 64], bp[s * 64], acc, 0, 0, 0);
    int g = ntile >> 7;
    int u = (ntile & 127) * 16 + (l & 15);
    #pragma unroll
    for (int i = 0; i < 4; ++i) {
        int b = 4 * (l >> 4) + i;    // D row = batch (m89-verified C/D layout)
        xz[((size_t)((t * 4 + g) * NBATCH) + b) * 2048 + u] = acc[i];
    }
}

// ---- Kernel S0: step 0 (h=c=0): z = xz(t=0); gates; write h,c,H[0],hA(bf16 A-frags) ----
__global__ __launch_bounds__(256) void k_step0(const float* __restrict__ xz,
        const float* __restrict__ ip, float* __restrict__ h, float* __restrict__ c,
        u16* __restrict__ hAout, float* __restrict__ H) {
    int idx = blockIdx.x * 256 + threadIdx.x;   // 0..32767
    int b = idx >> 11;
    int u = idx & 2047;
    float z0 = xz[((size_t)(0 * NBATCH) + b) * 2048 + u];
    float z1 = xz[((size_t)(1 * NBATCH) + b) * 2048 + u];
    float z2 = xz[((size_t)(2 * NBATCH) + b) * 2048 + u];
    float z3 = xz[((size_t)(3 * NBATCH) + b) * 2048 + u];
    (void)z1;
    float cn = sigmoidf_(z0) * tanhf(z2);
    float hn = sigmoidf_(z3) * tanhf(cn);
    int tok = token_of(ip[b * LAT + 0]);
    float hw = tok != 0 ? hn : 0.0f;
    float cw = tok != 0 ? cn : 0.0f;
    h[idx] = hw; c[idx] = cw; H[idx] = hw;
    int k0 = u >> 5, lg = (u >> 3) & 3, i = u & 7;   // k = u in next step's A
    hAout[((size_t)(k0 * 64) + lg * 16 + b) * 8 + i] = to_bf16(hw);
}

// ---- Kernel S: fused step t>=1: h @ Wr via MFMA + gates + masked update.
// 128 blocks (u-tile of 16) x 1024 thr = 16 waves: wave = (gate g, K-quarter kq).
__global__ __launch_bounds__(1024) void k_step(const u16* __restrict__ BW,
        const u16* __restrict__ hAin, u16* __restrict__ hAout,
        const float* __restrict__ xz, const float* __restrict__ ip,
        float* __restrict__ h, float* __restrict__ c,
        float* __restrict__ H, int t) {
    int tid = threadIdx.x;
    int w = tid >> 6;            // 0..15
    int g = w >> 2, kq = w & 3;
    int l = tid & 63;
    int bid = blockIdx.x;        // 0..127
    int ntile = g * 128 + bid;

    const bf16x8* ap = (const bf16x8*)(hAin + ((size_t)(kq * 16) * 64 + l) * 8);
    const bf16x8* bp = (const bf16x8*)(BW + (((size_t)ntile * 64 + kq * 16) * 64 + l) * 8);
    f32x4 acc = {0.f, 0.f, 0.f, 0.f};
    #pragma unroll
    for (int s = 0; s < 16; ++s)
        acc = __builtin_amdgcn_mfma_f32_16x16x32_bf16(ap[s * 64], bp[s * 64], acc, 0, 0, 0);

    __shared__ float zsh[16][256];
    #pragma unroll
    for (int i = 0; i < 4; ++i)
        zsh[w][(4 * (l >> 4) + i) * 16 + (l & 15)] = acc[i];
    __syncthreads();

    if (tid < 256) {
        int b = tid >> 4, ul = tid & 15;
        int u = bid * 16 + ul;
        float z[4];
        #pragma unroll
        for (int gg = 0; gg < 4; ++gg) {
            float s = zsh[gg * 4 + 0][tid] + zsh[gg * 4 + 1][tid]
                    + zsh[gg * 4 + 2][tid] + zsh[gg * 4 + 3][tid];
            z[gg] = s + xz[((size_t)((t * 4 + gg) * NBATCH) + b) * 2048 + u];
        }
        int idx = b * 2048 + u;
        float co = c[idx], ho = h[idx];
        float cn = sigmoidf_(z[1]) * co + sigmoidf_(z[0]) * tanhf(z[2]);
        float hn = sigmoidf_(z[3]) * tanhf(cn);
        int tok = token_of(ip[b * LAT + t]);
        float hw = tok != 0 ? hn : ho;
        float cw = tok != 0 ? cn : co;
        h[idx] = hw; c[idx] = cw;
        H[(size_t)t * (NBATCH * VOCAB) + idx] = hw;
        int k0 = u >> 5, lg = (u >> 3) & 3, i = u & 7;
        hAout[((size_t)(k0 * 64) + lg * 16 + b) * 8 + i] = to_bf16(hw);
    }
}

// ---- Kernel E: softmax of all 128 recorded h rows -> d_out[b][t][:] ----
__global__ __launch_bounds__(256) void k_softmax(const float* __restrict__ H,
                                                 float* __restrict__ out) {
    int r = blockIdx.x;          // r = t*16 + b
    int t = r >> 4, b = r & 15;
    int tid = threadIdx.x;
    const float* hr = H + (size_t)r * VOCAB;
    float v[8];
    float m = -1e30f;
    #pragma unroll
    for (int i = 0; i < 8; ++i) { v[i] = hr[tid + i * 256]; m = fmaxf(m, v[i]); }

    __shared__ float redm[4], reds[4];
    int wid = tid >> 6, lane = tid & 63;
    #pragma unroll
    for (int off = 32; off; off >>= 1) m = fmaxf(m, __shfl_down(m, off));
    if (lane == 0) redm[wid] = m;
    __syncthreads();
    m = fmaxf(fmaxf(redm[0], redm[1]), fmaxf(redm[2], redm[3]));

    float e[8];
    float s = 0.0f;
    #pragma unroll
    for (int i = 0; i < 8; ++i) { e[i] = expf(v[i] - m); s += e[i]; }
    #pragma unroll
    for (int off = 32; off; off >>= 1) s += __shfl_down(s, off);
    if (lane == 0) reds[wid] = s;
    __syncthreads();
    s = reds[0] + reds[1] + reds[2] + reds[3];

    float* o = out + ((size_t)b * MAXLEN + t) * VOCAB;
    #pragma unroll
    for (int i = 0; i < 8; ++i) o[tid + i * 256] = e[i] / s;
}

extern "C" void kernel_launch(void* const* d_in, const int* in_sizes, int n_in,
                              void* d_out, int out_size, void* d_ws, size_t ws_size,
                              hipStream_t stream) {
    const float* ip = (const float*)d_in[0];   // (16,16)
    const float* E  = (const float*)d_in[1];   // (2048,256)
    const float* Wk = (const float*)d_in[2];   // (256,8192)
    const float* Wr = (const float*)d_in[3];   // (2048,8192)
    const float* bv = (const float*)d_in[4];   // (8192,)

    char* w = (char*)d_ws;
    float* xz  = (float*)w;  w += (size_t)8 * 4 * NBATCH * 2048 * 4;   // 4 MB
    float* h   = (float*)w;  w += (size_t)32768 * 4;
    float* c   = (float*)w;  w += (size_t)32768 * 4;
    float* H   = (float*)w;  w += (size_t)262144 * 4;                  // 1 MB
    u16* XA  = (u16*)w;      w += (size_t)32768 * 2;                   // 64 KB
    u16* hA0 = (u16*)w;      w += (size_t)32768 * 2;
    u16* hA1 = (u16*)w;      w += (size_t)32768 * 2;
    u16* BWk = (u16*)w;      w += (size_t)2097152 * 2;                 // 4 MB
    u16* BW  = (u16*)w;      w += (size_t)16777216 * 2;                // 32 MB

    k_cvt<<<8192, 256, 0, stream>>>(Wr, BW, 6);    // 512 ntiles x 64 k0
    k_cvt<<<1024, 256, 0, stream>>>(Wk, BWk, 3);   // 512 ntiles x 8 k0
    k_init<<<16, 256, 0, stream>>>(ip, E, XA);
    k_xzmm<<<512, 512, 0, stream>>>(BWk, XA, bv, xz);
    k_step0<<<128, 256, 0, stream>>>(xz, ip, h, c, hA1, H);
    u16* hAbuf[2] = {hA0, hA1};
    for (int t = 1; t < MAXLEN; ++t)
        k_step<<<128, 1024, 0, stream>>>(BW, hAbuf[t & 1], hAbuf[(t + 1) & 1],
                                         xz, ip, h, c, H, t);
    k_softmax<<<128, 256, 0, stream>>>(H, (float*)d_out);
}

// Round 8
// 90.497 us; speedup vs baseline: 7.9450x; 1.0193x over previous
//
#include <hip/hip_runtime.h>
#include <hip/hip_bf16.h>
#include <math.h>

#define VOCAB 2048
#define EMB 256
#define MAXLEN 8
#define NBATCH 16
#define LAT 16

typedef unsigned short u16;
using bf16x8 = __attribute__((ext_vector_type(8))) short;
using f32x4  = __attribute__((ext_vector_type(4))) float;

// token = argmax_j ( j/2048 <= v && v <= (j+1)/2048 ), 0 if none.
// cumsum of uniform softmax is exactly k/2048 in fp32; v*2048 is exact.
__device__ __forceinline__ int token_of(float v) {
    float u = v * 2048.0f;
    if (!(u >= 0.0f) || u > 2048.0f) return 0;   // v<0, v>1, or NaN
    int k = (int)ceilf(u) - 1;
    return k < 0 ? 0 : k;
}

__device__ __forceinline__ float sigmoidf_(float x) { return 1.0f / (1.0f + expf(-x)); }

__device__ __forceinline__ u16 to_bf16(float x) {
    __hip_bfloat16 hb = __float2bfloat16(x);   // RTNE
    return *reinterpret_cast<u16*>(&hb);
}

// ---- Kernel CVT: pack W (K x 8192 fp32, K = 32<<sh) into MFMA-B fragment order.
// dst[((ntile*nk0 + k0)*64 + l)*8 + i] = bf16( W[(k0*32 + 8*(l>>4) + i)*8192 + ntile*16 + (l&15)] )
// (assumed per-lane k-map k = 8*(l>>4)+i; any k-permutation cancels since A uses the same map)
__global__ __launch_bounds__(256) void k_cvt(const float* __restrict__ W,
                                             u16* __restrict__ dst, int sh) {
    int gidx = blockIdx.x * 256 + threadIdx.x;
    int l = gidx & 63;
    int k0 = (gidx >> 6) & ((1 << sh) - 1);
    int ntile = gidx >> (6 + sh);
    int col = ntile * 16 + (l & 15);
    int row0 = k0 * 32 + 8 * (l >> 4);
    const float* s = W + (size_t)row0 * 8192 + col;
    u16 o[8];
    #pragma unroll
    for (int i = 0; i < 8; ++i) o[i] = to_bf16(s[(size_t)i * 8192]);
    *(uint4*)(dst + (size_t)gidx * 8) = *(uint4*)o;
}

// ---- Kernel PREP: blocks [0,1024): cvt Wk (sh=3); blocks [1024,1040): pack XA.
__global__ __launch_bounds__(256) void k_prep(const float* __restrict__ Wk,
                                              u16* __restrict__ BWk,
                                              const float* __restrict__ ip,
                                              const float* __restrict__ E,
                                              u16* __restrict__ XA) {
    int bx = blockIdx.x;
    if (bx < 1024) {
        int gidx = bx * 256 + threadIdx.x;
        int l = gidx & 63;
        int k0 = (gidx >> 6) & 7;
        int ntile = gidx >> 9;
        int col = ntile * 16 + (l & 15);
        int row0 = k0 * 32 + 8 * (l >> 4);
        const float* s = Wk + (size_t)row0 * 8192 + col;
        u16 o[8];
        #pragma unroll
        for (int i = 0; i < 8; ++i) o[i] = to_bf16(s[(size_t)i * 8192]);
        *(uint4*)(BWk + (size_t)gidx * 8) = *(uint4*)o;
    } else {
        int gidx = (bx - 1024) * 256 + threadIdx.x;   // 0..4095
        int l = gidx & 63;
        int k0 = (gidx >> 6) & 7;
        int t = gidx >> 9;
        int b = l & 15;
        int tok = token_of(ip[b * LAT + t]);
        const float* s = E + (size_t)tok * EMB + k0 * 32 + 8 * (l >> 4);
        u16 o[8];
        #pragma unroll
        for (int i = 0; i < 8; ++i) o[i] = to_bf16(s[i]);
        *(uint4*)(XA + (size_t)gidx * 8) = *(uint4*)o;
    }
}

// ---- Kernel B: xz[t][g][b][u] = bias + X[t] @ Wk, all 8 timesteps via MFMA.
// grid = 512 ntiles x 512 thr (8 waves = 8 timesteps). All 8 frags prefetched.
__global__ __launch_bounds__(512) void k_xzmm(const u16* __restrict__ BWk,
                                              const u16* __restrict__ XA,
                                              const float* __restrict__ bv,
                                              float* __restrict__ xz) {
    int ntile = blockIdx.x;          // 0..511 (n = ntile*16 + (l&15), n = g*2048+u)
    int t = threadIdx.x >> 6;        // 0..7
    int l = threadIdx.x & 63;
    float bias = bv[ntile * 16 + (l & 15)];
    f32x4 acc = {bias, bias, bias, bias};
    const bf16x8* ap = (const bf16x8*)(XA + ((size_t)(t * 8) * 64 + l) * 8);
    const bf16x8* bp = (const bf16x8*)(BWk + ((size_t)(ntile * 8) * 64 + l) * 8);
    bf16x8 av[8], bw[8];
    #pragma unroll
    for (int s = 0; s < 8; ++s) { av[s] = ap[s * 64]; bw[s] = bp[s * 64]; }
    #pragma unroll
    for (int s = 0; s < 8; ++s)
        acc = __builtin_amdgcn_mfma_f32_16x16x32_bf16(av[s], bw[s], acc, 0, 0, 0);
    int g = ntile >> 7;
    int u = (ntile & 127) * 16 + (l & 15);
    #pragma unroll
    for (int i = 0; i < 4; ++i) {
        int b = 4 * (l >> 4) + i;    // D row = batch (m89-verified C/D layout)
        xz[((size_t)((t * 4 + g) * NBATCH) + b) * 2048 + u] = acc[i];
    }
}

// ---- Kernel S0: step 0 (h=c=0): z = xz(t=0); gates; write h,c,H[0],hA(bf16 A-frags) ----
__global__ __launch_bounds__(256) void k_step0(const float* __restrict__ xz,
        const float* __restrict__ ip, float* __restrict__ h, float* __restrict__ c,
        u16* __restrict__ hAout, float* __restrict__ H) {
    int idx = blockIdx.x * 256 + threadIdx.x;   // 0..32767
    int b = idx >> 11;
    int u = idx & 2047;
    float z0 = xz[((size_t)(0 * NBATCH) + b) * 2048 + u];
    float z2 = xz[((size_t)(2 * NBATCH) + b) * 2048 + u];
    float z3 = xz[((size_t)(3 * NBATCH) + b) * 2048 + u];
    float cn = sigmoidf_(z0) * tanhf(z2);
    float hn = sigmoidf_(z3) * tanhf(cn);
    int tok = token_of(ip[b * LAT + 0]);
    float hw = tok != 0 ? hn : 0.0f;
    float cw = tok != 0 ? cn : 0.0f;
    h[idx] = hw; c[idx] = cw; H[idx] = hw;
    int k0 = u >> 5, lg = (u >> 3) & 3, i = u & 7;   // k = u in next step's A
    hAout[((size_t)(k0 * 64) + lg * 16 + b) * 8 + i] = to_bf16(hw);
}

// ---- Kernel S: fused step t>=1: h @ Wr via MFMA + gates + masked update.
// 128 blocks (u-tile of 16) x 1024 thr = 16 waves: wave = (gate g, K-quarter kq).
// B-fragments register-prefetched 8-deep, A 4-deep (covers ~400cy L3 latency).
__global__ __launch_bounds__(1024) void k_step(const u16* __restrict__ BW,
        const u16* __restrict__ hAin, u16* __restrict__ hAout,
        const float* __restrict__ xz, const float* __restrict__ ip,
        float* __restrict__ h, float* __restrict__ c,
        float* __restrict__ H, int t) {
    int tid = threadIdx.x;
    int w = tid >> 6;            // 0..15
    int g = w >> 2, kq = w & 3;
    int l = tid & 63;
    int bid = blockIdx.x;        // 0..127
    int ntile = g * 128 + bid;

    const bf16x8* ap = (const bf16x8*)(hAin + ((size_t)(kq * 16) * 64 + l) * 8);
    const bf16x8* bp = (const bf16x8*)(BW + (((size_t)ntile * 64 + kq * 16) * 64 + l) * 8);
    f32x4 acc = {0.f, 0.f, 0.f, 0.f};

    bf16x8 br[8], ar[4];
    #pragma unroll
    for (int i = 0; i < 8; ++i) br[i] = bp[i * 64];
    #pragma unroll
    for (int i = 0; i < 4; ++i) ar[i] = ap[i * 64];

    #pragma unroll
    for (int s = 0; s < 16; ++s) {
        bf16x8 a = ar[s & 3];
        bf16x8 b = br[s & 7];
        if (s + 4 < 16) ar[s & 3] = ap[(s + 4) * 64];
        if (s + 8 < 16) br[s & 7] = bp[(s + 8) * 64];
        acc = __builtin_amdgcn_mfma_f32_16x16x32_bf16(a, b, acc, 0, 0, 0);
    }

    __shared__ float zsh[16][256];
    #pragma unroll
    for (int i = 0; i < 4; ++i)
        zsh[w][(4 * (l >> 4) + i) * 16 + (l & 15)] = acc[i];
    __syncthreads();

    if (tid < 256) {
        int b = tid >> 4, ul = tid & 15;
        int u = bid * 16 + ul;
        float z[4];
        #pragma unroll
        for (int gg = 0; gg < 4; ++gg) {
            float s = zsh[gg * 4 + 0][tid] + zsh[gg * 4 + 1][tid]
                    + zsh[gg * 4 + 2][tid] + zsh[gg * 4 + 3][tid];
            z[gg] = s + xz[((size_t)((t * 4 + gg) * NBATCH) + b) * 2048 + u];
        }
        int idx = b * 2048 + u;
        float co = c[idx], ho = h[idx];
        float cn = sigmoidf_(z[1]) * co + sigmoidf_(z[0]) * tanhf(z[2]);
        float hn = sigmoidf_(z[3]) * tanhf(cn);
        int tok = token_of(ip[b * LAT + t]);
        float hw = tok != 0 ? hn : ho;
        float cw = tok != 0 ? cn : co;
        h[idx] = hw; c[idx] = cw;
        H[(size_t)t * (NBATCH * VOCAB) + idx] = hw;
        int k0 = u >> 5, lg = (u >> 3) & 3, i = u & 7;
        hAout[((size_t)(k0 * 64) + lg * 16 + b) * 8 + i] = to_bf16(hw);
    }
}

// ---- Kernel E: softmax of all 128 recorded h rows -> d_out[b][t][:] ----
__global__ __launch_bounds__(256) void k_softmax(const float* __restrict__ H,
                                                 float* __restrict__ out) {
    int r = blockIdx.x;          // r = t*16 + b
    int t = r >> 4, b = r & 15;
    int tid = threadIdx.x;
    const float* hr = H + (size_t)r * VOCAB;
    float v[8];
    float m = -1e30f;
    #pragma unroll
    for (int i = 0; i < 8; ++i) { v[i] = hr[tid + i * 256]; m = fmaxf(m, v[i]); }

    __shared__ float redm[4], reds[4];
    int wid = tid >> 6, lane = tid & 63;
    #pragma unroll
    for (int off = 32; off; off >>= 1) m = fmaxf(m, __shfl_down(m, off));
    if (lane == 0) redm[wid] = m;
    __syncthreads();
    m = fmaxf(fmaxf(redm[0], redm[1]), fmaxf(redm[2], redm[3]));

    float e[8];
    float s = 0.0f;
    #pragma unroll
    for (int i = 0; i < 8; ++i) { e[i] = expf(v[i] - m); s += e[i]; }
    #pragma unroll
    for (int off = 32; off; off >>= 1) s += __shfl_down(s, off);
    if (lane == 0) reds[wid] = s;
    __syncthreads();
    s = reds[0] + reds[1] + reds[2] + reds[3];

    float* o = out + ((size_t)b * MAXLEN + t) * VOCAB;
    #pragma unroll
    for (int i = 0; i < 8; ++i) o[tid + i * 256] = e[i] / s;
}

extern "C" void kernel_launch(void* const* d_in, const int* in_sizes, int n_in,
                              void* d_out, int out_size, void* d_ws, size_t ws_size,
                              hipStream_t stream) {
    const float* ip = (const float*)d_in[0];   // (16,16)
    const float* E  = (const float*)d_in[1];   // (2048,256)
    const float* Wk = (const float*)d_in[2];   // (256,8192)
    const float* Wr = (const float*)d_in[3];   // (2048,8192)
    const float* bv = (const float*)d_in[4];   // (8192,)

    char* w = (char*)d_ws;
    float* xz  = (float*)w;  w += (size_t)8 * 4 * NBATCH * 2048 * 4;   // 4 MB
    float* h   = (float*)w;  w += (size_t)32768 * 4;
    float* c   = (float*)w;  w += (size_t)32768 * 4;
    float* H   = (float*)w;  w += (size_t)262144 * 4;                  // 1 MB
    u16* XA  = (u16*)w;      w += (size_t)32768 * 2;                   // 64 KB
    u16* hA0 = (u16*)w;      w += (size_t)32768 * 2;
    u16* hA1 = (u16*)w;      w += (size_t)32768 * 2;
    u16* BWk = (u16*)w;      w += (size_t)2097152 * 2;                 // 4 MB
    u16* BW  = (u16*)w;      w += (size_t)16777216 * 2;                // 32 MB

    k_cvt<<<8192, 256, 0, stream>>>(Wr, BW, 6);      // 512 ntiles x 64 k0
    k_prep<<<1040, 256, 0, stream>>>(Wk, BWk, ip, E, XA);
    k_xzmm<<<512, 512, 0, stream>>>(BWk, XA, bv, xz);
    k_step0<<<128, 256, 0, stream>>>(xz, ip, h, c, hA1, H);
    u16* hAbuf[2] = {hA0, hA1};
    for (int t = 1; t < MAXLEN; ++t)
        k_step<<<128, 1024, 0, stream>>>(BW, hAbuf[t & 1], hAbuf[(t + 1) & 1],
                                         xz, ip, h, c, H, t);
    k_softmax<<<128, 256, 0, stream>>>(H, (float*)d_out);
}